// Round 11
// baseline (84.305 us; speedup 1.0000x reference)
//
#include <hip/hip_runtime.h>

// DTW via min-plus scan for MI355X (gfx950). Round 11.
// B=32, N=32, D=12, P=32, L=1024, L_OUT=32, RHO=1 => w=1.
// Row recurrence as prefix scan:  S[j] = prefix_sum(cost[i,:]),
//   D[j] = S[j] + prefix_min_k(a[k]-S[k-1]),  a[k]=min(Dprev[k-1],Dprev[k]).
// r11: each (b,n) problem split across 2 waves (512 cols each, 8 cols/lane).
// 1024 blocks x 128 thr = 2048 waves = 2 waves/SIMD (TLP=2, first time >1)
// and ~180 VGPRs/wave (no spill). Cross-wave: 3 scalars per row through LDS,
// one __syncthreads per row; wave1's scans run pre-barrier with BIG-seeded
// boundary, corrected post-barrier by two scalar mins.

#define BIGF 1e30f
#define LL   1024
#define LOUT 32

using v4f = __attribute__((ext_vector_type(4))) float;

template<int CTRL>
__device__ __forceinline__ float dpp_self(float v) {   // invalid lanes keep own
    return __int_as_float(__builtin_amdgcn_update_dpp(
        __float_as_int(v), __float_as_int(v), CTRL, 0xF, 0xF, false));
}
// validated r2-r10: whole-wave shift right 1 lane; lane 0 <- 0
__device__ __forceinline__ float wshr1z(float v) {
    return __int_as_float(__builtin_amdgcn_update_dpp(
        0, __float_as_int(v), 0x138 /*wave_shr:1*/, 0xF, 0xF, false));
}
__device__ __forceinline__ float rdlane(float v, int l) {
    return __int_as_float(__builtin_amdgcn_readlane(__float_as_int(v), l));
}

// inclusive wave64 min-scan (r9/r10-validated): 4 dpp row_shr + readlane combine
__device__ __forceinline__ float scan_min64_fast(float t, int lane) {
    t = fminf(t, dpp_self<0x111>(t));
    t = fminf(t, dpp_self<0x112>(t));
    t = fminf(t, dpp_self<0x114>(t));
    t = fminf(t, dpp_self<0x118>(t));
    float r0 = rdlane(t, 15), r1 = rdlane(t, 31), r2 = rdlane(t, 47);
    t = fminf(t, (lane >= 16) ? r0 : BIGF);
    t = fminf(t, (lane >= 32) ? r1 : BIGF);
    t = fminf(t, (lane >= 48) ? r2 : BIGF);
    return t;
}
// setup-only (r8-validated): shfl_up add scan
__device__ __forceinline__ float scan_add64(float t, int lane) {
#pragma unroll
    for (int d = 1; d < 64; d <<= 1) {
        float o = __shfl_up(t, (unsigned)d, 64);
        t += (lane >= d) ? o : 0.0f;
    }
    return t;
}

__global__ __launch_bounds__(128)
__attribute__((amdgpu_waves_per_eu(2, 2)))
void dtw_kernel(const float* __restrict__ x, const float* __restrict__ patts,
                float* __restrict__ out) {
    __shared__ float pT[32 * 12];   // -2*patts[n], layout [i][d]
    __shared__ float p2s[32];
    __shared__ float wtot[13];      // wave0 prefix-sum totals (12 SXd + SX2)
    __shared__ float bnd[2][3];     // per-row: {Dprev[511], S[511], T0}, dbuf

    const int tid  = threadIdx.x;
    const int wid  = tid >> 6;             // 0: cols 0..511, 1: cols 512..1023
    const int lane = tid & 63;
    const bool l0  = (lane == 0);
    const int blk  = blockIdx.x;           // (b,n)
    const int b    = blk >> 5, n = blk & 31;
    const float* __restrict__ xb = x + b * (12 * LL);
    const float* __restrict__ pn = patts + n * (12 * 32);

    // ---- patts transpose (scaled by -2) + p2 (wave0 lanes 0..31) ----
    if (tid < 32) {
        float s2 = 0.f;
#pragma unroll
        for (int d = 0; d < 12; ++d) {
            float v = pn[d * 32 + tid];
            s2 = fmaf(v, v, s2);
            pT[tid * 12 + d] = -2.0f * v;
        }
        p2s[tid] = s2;
    }

    // ---- x slice -> regs: 8 consecutive cols per lane ----
    const int col0 = 512 * wid + 8 * lane;
    float SX[12][8];
#pragma unroll
    for (int d = 0; d < 12; ++d) {
        v4f a = *(const v4f*)(xb + d * LL + col0);
        v4f c = *(const v4f*)(xb + d * LL + col0 + 4);
        SX[d][0] = a.x; SX[d][1] = a.y; SX[d][2] = a.z; SX[d][3] = a.w;
        SX[d][4] = c.x; SX[d][5] = c.y; SX[d][6] = c.z; SX[d][7] = c.w;
    }
    float SX2[8];
#pragma unroll
    for (int k = 0; k < 8; ++k) {
        float a = 0.f;
#pragma unroll
        for (int d = 0; d < 12; ++d) a = fmaf(SX[d][k], SX[d][k], a);
        SX2[k] = a;
    }
    // ---- wave-local inclusive prefix sums + publish wave0 totals ----
#pragma unroll
    for (int d = 0; d < 12; ++d) {
#pragma unroll
        for (int k = 1; k < 8; ++k) SX[d][k] += SX[d][k-1];
        float tot  = SX[d][7];
        float incl = scan_add64(tot, lane);
        float ex   = incl - tot;
#pragma unroll
        for (int k = 0; k < 8; ++k) SX[d][k] += ex;
        if (wid == 0 && lane == 63) wtot[d] = incl;
    }
    {
#pragma unroll
        for (int k = 1; k < 8; ++k) SX2[k] += SX2[k-1];
        float tot  = SX2[7];
        float incl = scan_add64(tot, lane);
        float ex   = incl - tot;
#pragma unroll
        for (int k = 0; k < 8; ++k) SX2[k] += ex;
        if (wid == 0 && lane == 63) wtot[12] = incl;
    }
    __syncthreads();
    if (wid == 1) {   // make prefix sums global
#pragma unroll
        for (int d = 0; d < 12; ++d) {
            float o = wtot[d];
#pragma unroll
            for (int k = 0; k < 8; ++k) SX[d][k] += o;
        }
        float o2 = wtot[12];
#pragma unroll
        for (int k = 0; k < 8; ++k) SX2[k] += o2;
    }
    float jp1[8];
#pragma unroll
    for (int k = 0; k < 8; ++k) jp1[k] = (float)(col0 + k + 1);

    float* ob = out + blk * (32 * LOUT) + (col0 - (LL - LOUT));  // wave1 lanes>=60

    // ---- row 0: D = S(row 0) ----
    float S[8], Dp[8];
    {
        float pv[12];
#pragma unroll
        for (int d = 0; d < 12; ++d) pv[d] = pT[d];
        float p2u = p2s[0];
#pragma unroll
        for (int k = 0; k < 8; ++k) S[k] = fmaf(p2u, jp1[k], SX2[k]);
#pragma unroll
        for (int d = 0; d < 12; ++d)
#pragma unroll
            for (int k = 0; k < 8; ++k) S[k] = fmaf(pv[d], SX[d][k], S[k]);
#pragma unroll
        for (int k = 0; k < 8; ++k) Dp[k] = S[k];
        if (wid == 1 && lane >= 60) {
            v4f v0 = {Dp[0], Dp[1], Dp[2], Dp[3]};
            v4f v1 = {Dp[4], Dp[5], Dp[6], Dp[7]};
            *(v4f*)(ob + 0) = v0;
            *(v4f*)(ob + 4) = v1;
        }
    }

    // ---- rows 1..31, one barrier per row ----
#pragma unroll 1
    for (int i = 1; i < 32; ++i) {
        const int s = i & 1;
        // boundary publish value from previous row (wave0 only, pre-barrier)
        float dbv = rdlane(Dp[7], 63);    // Dprev[511]

        // S(row i)
        float pv[12];
#pragma unroll
        for (int d = 0; d < 12; ++d) pv[d] = pT[i * 12 + d];
        float p2u = p2s[i];
#pragma unroll
        for (int k = 0; k < 8; ++k) S[k] = fmaf(p2u, jp1[k], SX2[k]);
#pragma unroll
        for (int d = 0; d < 12; ++d)
#pragma unroll
            for (int k = 0; k < 8; ++k) S[k] = fmaf(pv[d], SX[d][k], S[k]);

        // z / local inclusive min-scan m (wave-local; wave1 lane0 seeded BIG)
        float dsh = wshr1z(Dp[7]);                  // left-neighbor Dprev
        float se  = wshr1z(S[7]);                   // left-neighbor S (lane0->0)
        float z0  = fminf(l0 ? BIGF : dsh, Dp[0]) - se;
        if (wid == 1 && l0) z0 = BIGF;              // corrected post-barrier
        float m[8];
        m[0] = z0;
#pragma unroll
        for (int k = 1; k < 8; ++k)
            m[k] = fminf(m[k-1], fminf(Dp[k-1], Dp[k]) - S[k-1]);

        float t   = scan_min64_fast(m[7], lane);    // inclusive over lane totals
        float te  = wshr1z(t); te = l0 ? BIGF : te; // exclusive-from-left

        if (wid == 0) {
            float sbv = rdlane(S[7], 63);           // S[i][511]
            float T0v = rdlane(t, 63);              // wave0 full-row min total
            if (l0) { bnd[s][0] = dbv; bnd[s][1] = sbv; bnd[s][2] = T0v; }
        }
        __syncthreads();

        float B;
        if (wid == 0) {
            B = te;
        } else {
            float dsh_b = bnd[s][0], se_b = bnd[s][1], T0 = bnd[s][2];
            float d0  = rdlane(Dp[0], 0);           // wave1 Dprev[512]
            float z0c = fminf(dsh_b, d0) - se_b;    // true z at col 512
            B = fminf(fminf(T0, z0c), te);
        }
#pragma unroll
        for (int k = 0; k < 8; ++k) Dp[k] = S[k] + fminf(B, m[k]);

        if (wid == 1 && lane >= 60) {
            v4f v0 = {Dp[0], Dp[1], Dp[2], Dp[3]};
            v4f v1 = {Dp[4], Dp[5], Dp[6], Dp[7]};
            *(v4f*)(ob + i * 32 + 0) = v0;
            *(v4f*)(ob + i * 32 + 4) = v1;
        }
    }
}

extern "C" void kernel_launch(void* const* d_in, const int* in_sizes, int n_in,
                              void* d_out, int out_size, void* d_ws, size_t ws_size,
                              hipStream_t stream) {
    const float* x     = (const float*)d_in[0];   // [32,12,1024] f32
    const float* patts = (const float*)d_in[1];   // [32,12,32]   f32
    float* out         = (float*)d_out;           // [32,32,32,32] f32
    dtw_kernel<<<dim3(1024), dim3(128), 0, stream>>>(x, patts, out);
}

// Round 12
// 80.310 us; speedup vs baseline: 1.0497x; 1.0497x over previous
//
#include <hip/hip_runtime.h>

// DTW via min-plus scan for MI355X (gfx950). Round 12.
// B=32, N=32, D=12, P=32, L=1024, L_OUT=32, RHO=1 => w=1.
// Row recurrence as prefix scan:  S[j] = prefix_sum(cost[i,:]),
//   D[j] = S[j] + prefix_min_k(a[k]-S[k-1]),  a[k]=min(Dprev[k-1],Dprev[k]).
// Lanes = columns (16 cols/lane, one wave per (b,n) problem). Rows serial.
// r12 vs r8-r11 (all ~same speed): unified diagnosis — every row loop so far
// did ~13 LDS broadcast reads (pT/p2s) at ~120cyc single-outstanding latency
// (m117) which the pressure-constrained scheduler never batched (~1.6k
// cyc/row), + (r11) a per-row barrier drain. r12 row loop has ZERO LDS:
// pattern params live in registers of lanes 0..31 (lane r = row r) and are
// fetched per row via v_readlane (SALU). No __shared__, no barriers, no Sn
// pipeline. waves_per_eu(1,1) -> ~450-reg no-spill budget for ~300 live.

#define BIGF 1e30f
#define LL   1024
#define LOUT 32

using v4f = __attribute__((ext_vector_type(4))) float;

template<int CTRL>
__device__ __forceinline__ float dpp_self(float v) {   // invalid lanes keep own
    return __int_as_float(__builtin_amdgcn_update_dpp(
        __float_as_int(v), __float_as_int(v), CTRL, 0xF, 0xF, false));
}
// validated r2-r11: whole-wave shift right 1 lane; lane 0 <- 0
__device__ __forceinline__ float wshr1z(float v) {
    return __int_as_float(__builtin_amdgcn_update_dpp(
        0, __float_as_int(v), 0x138 /*wave_shr:1*/, 0xF, 0xF, false));
}
__device__ __forceinline__ float rdlane(float v, int l) {
    return __int_as_float(__builtin_amdgcn_readlane(__float_as_int(v), l));
}

// inclusive wave64 min-scan (r9/r10-validated): 4 dpp row_shr + readlane combine
__device__ __forceinline__ float scan_min64_fast(float t, int lane) {
    t = fminf(t, dpp_self<0x111>(t));   // row_shr:1
    t = fminf(t, dpp_self<0x112>(t));   // row_shr:2
    t = fminf(t, dpp_self<0x114>(t));   // row_shr:4
    t = fminf(t, dpp_self<0x118>(t));   // row_shr:8
    float r0 = rdlane(t, 15), r1 = rdlane(t, 31), r2 = rdlane(t, 47);
    t = fminf(t, (lane >= 16) ? r0 : BIGF);
    t = fminf(t, (lane >= 32) ? r1 : BIGF);
    t = fminf(t, (lane >= 48) ? r2 : BIGF);
    return t;
}
// setup-only (r8-validated): shfl_up add scan
__device__ __forceinline__ float scan_add64(float t, int lane) {
#pragma unroll
    for (int d = 1; d < 64; d <<= 1) {
        float o = __shfl_up(t, (unsigned)d, 64);
        t += (lane >= d) ? o : 0.0f;
    }
    return t;
}

__global__ __launch_bounds__(64)
__attribute__((amdgpu_waves_per_eu(1, 1)))   // 1 wave/EU: full register file
void dtw_kernel(const float* __restrict__ x, const float* __restrict__ patts,
                float* __restrict__ out) {
    const int lane = threadIdx.x;          // lane owns cols [16*lane, 16*lane+16)
    const bool l0  = (lane == 0);
    const int blk  = blockIdx.x;           // 0..1023 = (b,n)
    const int b    = blk >> 5, n = blk & 31;
    const float* __restrict__ xb = x + b * (12 * LL);
    const float* __restrict__ pn = patts + n * (12 * 32);

    // ---- pattern params into registers: lane r (r&31) holds row r ----
    float prm[12], p2r;
    {
        const int r = lane & 31;
        float s2 = 0.f;
#pragma unroll
        for (int d = 0; d < 12; ++d) {
            float v = pn[d * 32 + r];
            s2 = fmaf(v, v, s2);
            prm[d] = -2.0f * v;
        }
        p2r = s2;
    }

    // ---- x slice -> regs (coalesced 16B/lane) ----
    float SX[12][16];
#pragma unroll
    for (int d = 0; d < 12; ++d) {
#pragma unroll
        for (int c = 0; c < 4; ++c) {
            v4f v = *(const v4f*)(xb + d * LL + 16 * lane + 4 * c);
            SX[d][4*c+0] = v.x; SX[d][4*c+1] = v.y;
            SX[d][4*c+2] = v.z; SX[d][4*c+3] = v.w;
        }
    }
    float SX2[16];
#pragma unroll
    for (int k = 0; k < 16; ++k) {
        float a = 0.f;
#pragma unroll
        for (int d = 0; d < 12; ++d) a = fmaf(SX[d][k], SX[d][k], a);
        SX2[k] = a;
    }
    // ---- inclusive prefix sums: intra-lane serial + cross-lane shfl scan ----
#pragma unroll
    for (int d = 0; d < 12; ++d) {
#pragma unroll
        for (int k = 1; k < 16; ++k) SX[d][k] += SX[d][k-1];
        float tot = SX[d][15];
        float ex  = scan_add64(tot, lane) - tot;   // exclusive lane offset
#pragma unroll
        for (int k = 0; k < 16; ++k) SX[d][k] += ex;
    }
    {
#pragma unroll
        for (int k = 1; k < 16; ++k) SX2[k] += SX2[k-1];
        float tot = SX2[15];
        float ex  = scan_add64(tot, lane) - tot;
#pragma unroll
        for (int k = 0; k < 16; ++k) SX2[k] += ex;
    }
    float jp1[16];
#pragma unroll
    for (int k = 0; k < 16; ++k) jp1[k] = (float)(16 * lane + k + 1);

    // ---- row 0: D = S(row 0) ----
    float S[16], Dp[16];
    {
        float pv[12], p2u;
#pragma unroll
        for (int d = 0; d < 12; ++d) pv[d] = rdlane(prm[d], 0);
        p2u = rdlane(p2r, 0);
#pragma unroll
        for (int k = 0; k < 16; ++k) S[k] = fmaf(p2u, jp1[k], SX2[k]);
#pragma unroll
        for (int d = 0; d < 12; ++d)
#pragma unroll
            for (int k = 0; k < 16; ++k) S[k] = fmaf(pv[d], SX[d][k], S[k]);
#pragma unroll
        for (int k = 0; k < 16; ++k) Dp[k] = S[k];
        if (lane >= 62) {
            float* ob = out + blk * (32 * LOUT) + (lane - 62) * 16;
#pragma unroll
            for (int c = 0; c < 4; ++c) {
                v4f v = {Dp[4*c], Dp[4*c+1], Dp[4*c+2], Dp[4*c+3]};
                *(v4f*)(ob + 4 * c) = v;
            }
        }
    }

    // ---- rows 1..31: zero LDS, zero barriers ----
#pragma unroll 1
    for (int i = 1; i < 32; ++i) {
        // row params via readlane (SALU broadcast, i is wave-uniform)
        float pv[12], p2u;
#pragma unroll
        for (int d = 0; d < 12; ++d) pv[d] = rdlane(prm[d], i);
        p2u = rdlane(p2r, i);

        // S(row i) for this lane's 16 columns
#pragma unroll
        for (int k = 0; k < 16; ++k) S[k] = fmaf(p2u, jp1[k], SX2[k]);
#pragma unroll
        for (int d = 0; d < 12; ++d)
#pragma unroll
            for (int k = 0; k < 16; ++k) S[k] = fmaf(pv[d], SX[d][k], S[k]);

        // boundary values from the left neighbor (validated primitive)
        float dsh = wshr1z(Dp[15]); dsh = l0 ? BIGF : dsh;  // D_prev[j-1] at k=0
        float se  = wshr1z(S[15]);                          // S[j-1] at k=0 (lane0->0)

        // z[k] = a[k] - S[k-1]; intra-lane inclusive min-scan m
        float m[16];
        m[0] = fminf(dsh, Dp[0]) - se;
#pragma unroll
        for (int k = 1; k < 16; ++k)
            m[k] = fminf(m[k-1], fminf(Dp[k-1], Dp[k]) - S[k-1]);

        // cross-lane inclusive min-scan of lane totals, then exclusive
        float t  = scan_min64_fast(m[15], lane);
        float te = wshr1z(t); te = l0 ? BIGF : te;

#pragma unroll
        for (int k = 0; k < 16; ++k) Dp[k] = S[k] + fminf(te, m[k]);

        if (lane >= 62) {
            float* ob = out + blk * (32 * LOUT) + (lane - 62) * 16;
#pragma unroll
            for (int c = 0; c < 4; ++c) {
                v4f v = {Dp[4*c], Dp[4*c+1], Dp[4*c+2], Dp[4*c+3]};
                *(v4f*)(ob + i * 32 + 4 * c) = v;
            }
        }
    }
}

extern "C" void kernel_launch(void* const* d_in, const int* in_sizes, int n_in,
                              void* d_out, int out_size, void* d_ws, size_t ws_size,
                              hipStream_t stream) {
    const float* x     = (const float*)d_in[0];   // [32,12,1024] f32
    const float* patts = (const float*)d_in[1];   // [32,12,32]   f32
    float* out         = (float*)d_out;           // [32,32,32,32] f32
    dtw_kernel<<<dim3(1024), dim3(64), 0, stream>>>(x, patts, out);
}